// Round 15
// baseline (479.152 us; speedup 1.0000x reference)
//
#include <hip/hip_runtime.h>

typedef unsigned short u16;
typedef __bf16  bf16x8 __attribute__((ext_vector_type(8)));
typedef float   f32x4  __attribute__((ext_vector_type(4)));
typedef unsigned short us8 __attribute__((ext_vector_type(8)));
typedef _Float16 f16x8 __attribute__((ext_vector_type(8)));
typedef float   fl4   __attribute__((ext_vector_type(4)));

#define AS1 __attribute__((address_space(1)))
#define AS3 __attribute__((address_space(3)))

__device__ __forceinline__ u16 f2bf(float f) {
    union { float f; unsigned u; } x; x.f = f;
    unsigned r = x.u + 0x7fffu + ((x.u >> 16) & 1u);
    return (u16)(r >> 16);
}

// ---------------- fused fp32->bf16 projections, all 3 in ONE dispatch ----------------
// C = A(fp32) * B(fp32)^T + bias, output bf16. Register-staging replaces
// global_load_lds: per K-tile, 16 global fl4-pair loads -> in-reg f2bf ->
// swizzled ds_write_b128 (same physical LDS layout as the DMA path, so the
// proven frag-read side is byte-identical). Drain-all __syncthreads covers
// ds_writes + reads -> race-free by construction. blockIdx.y routes
// {pq, pk, pvT}; eliminates the separate cast kernel entirely.
__global__ __launch_bounds__(512, 2) void proj3f(const float* __restrict__ q,
                                                 const float* __restrict__ k,
                                                 const float* __restrict__ v,
                                                 const float* __restrict__ Wq,
                                                 const float* __restrict__ Wk,
                                                 const float* __restrict__ Wv,
                                                 u16* __restrict__ pq, u16* __restrict__ pk,
                                                 u16* __restrict__ pvT,
                                                 const float* __restrict__ bq,
                                                 const float* __restrict__ bk,
                                                 const float* __restrict__ bv,
                                                 int E, int NBL) {
    __shared__ alignas(16) char lds8[2 * 65536];

    const int t    = threadIdx.x;
    const int lane = t & 63;
    const int wid  = t >> 6;
    const int wr   = wid >> 2;    // 0..1
    const int wc   = wid & 3;     // 0..3
    const int fr   = lane & 15;
    const int kq   = lane >> 4;

    // route the three sub-GEMMs
    const int y  = blockIdx.y;
    const int bx = blockIdx.x;                  // 0..255
    const int swz = (bx & 7) * 32 + (bx >> 3);  // XCD-bijective (256%8==0)
    const float *A, *B, *bias; u16* C; int ldc, tx, ty, mode;
    if (y < 2) {   // pq/pk = x @ W^T + b[col]: M=16384 (ty 0..63), N=1024 (tx 0..3)
        A = y ? k : q; B = y ? Wk : Wq; C = y ? pk : pq; bias = y ? bk : bq;
        ldc = E; tx = swz & 3; ty = swz >> 2; mode = 0;
    } else {       // pvT = Wv @ v^T + bv[row]: M=1024 (ty 0..3), N=16384 (tx 0..63)
        A = Wv; B = v; C = pvT; bias = bv;
        ldc = NBL; tx = swz & 63; ty = swz >> 6; mode = 1;
    }
    const long brow = (long)ty * 256;
    const long bcol = (long)tx * 256;

    // staging geometry: round r covers rows r*64+(t>>3); logical chunk
    // Lc=(t&7)^(row&7) pre-swizzled into the SOURCE; phys dest = r*8192+t*16.
    const int trow = t >> 3;
    const int Lc8  = ((t & 7) ^ (trow & 7)) * 8;   // fp32 element offset
    long offA[4], offB[4];
#pragma unroll
    for (int r = 0; r < 4; ++r) offA[r] = (brow + r * 64 + trow) * (long)E + Lc8;
#pragma unroll
    for (int r = 0; r < 4; ++r) offB[r] = (bcol + r * 64 + trow) * (long)E + Lc8;

    // frag read offsets (identical to gemm256d)
    int aRow[8], bRow[4], aCh[2];
#pragma unroll
    for (int m = 0; m < 8; ++m) aRow[m] = (wr * 128 + m * 16 + fr) * 128;
#pragma unroll
    for (int n = 0; n < 4; ++n) bRow[n] = 32768 + (wc * 64 + n * 16 + fr) * 128;
#pragma unroll
    for (int ks = 0; ks < 2; ++ks) aCh[ks] = (((ks << 2) | kq) ^ (fr & 7)) * 16;

    const int NT = E >> 6;   // 16
    f32x4 acc[8][4] = {};

    // prologue: reg-stage tile 0 into buffer 0
    {
#pragma unroll
        for (int r = 0; r < 4; ++r) {
            const float* pA = A + offA[r];
            fl4 a0 = *(const fl4*)pA, a1 = *(const fl4*)(pA + 4);
            us8 w;
#pragma unroll
            for (int j = 0; j < 4; ++j) { w[j] = f2bf(a0[j]); w[4 + j] = f2bf(a1[j]); }
            *(us8*)(lds8 + r * 8192 + t * 16) = w;
        }
#pragma unroll
        for (int r = 0; r < 4; ++r) {
            const float* pB = B + offB[r];
            fl4 b0 = *(const fl4*)pB, b1 = *(const fl4*)(pB + 4);
            us8 w;
#pragma unroll
            for (int j = 0; j < 4; ++j) { w[j] = f2bf(b0[j]); w[4 + j] = f2bf(b1[j]); }
            *(us8*)(lds8 + 32768 + r * 8192 + t * 16) = w;
        }
    }
    __syncthreads();

    int cur = 0;
    for (int T = 0; T < NT; ++T) {
        char* bb  = lds8 + cur * 65536;
        char* bbn = lds8 + (cur ^ 1) * 65536;
        const bool st = (T + 1) < NT;

        // 1) issue next tile's global loads into named regs (latency hides
        //    under the frag-read + MFMA section below)
        fl4 sa0[4], sa1[4], sb0[4], sb1[4];
        if (st) {
            const long kc = (long)(T + 1) << 6;
#pragma unroll
            for (int r = 0; r < 4; ++r) {
                const float* pA = A + offA[r] + kc;
                sa0[r] = *(const fl4*)pA; sa1[r] = *(const fl4*)(pA + 4);
                const float* pB = B + offB[r] + kc;
                sb0[r] = *(const fl4*)pB; sb1[r] = *(const fl4*)(pB + 4);
            }
        }

        // 2) frag reads + MFMAs (two ksub phases, disjoint frag regs)
        bf16x8 af0[8], bf0[4], af1[8], bf1[4];
#pragma unroll
        for (int n = 0; n < 4; ++n) bf0[n] = *(const bf16x8*)(bb + bRow[n] + aCh[0]);
#pragma unroll
        for (int m = 0; m < 8; ++m) af0[m] = *(const bf16x8*)(bb + aRow[m] + aCh[0]);
#pragma unroll
        for (int m = 0; m < 8; ++m)
#pragma unroll
            for (int n = 0; n < 4; ++n)
                acc[m][n] = __builtin_amdgcn_mfma_f32_16x16x32_bf16(af0[m], bf0[n], acc[m][n], 0, 0, 0);

#pragma unroll
        for (int n = 0; n < 4; ++n) bf1[n] = *(const bf16x8*)(bb + bRow[n] + aCh[1]);
#pragma unroll
        for (int m = 0; m < 8; ++m) af1[m] = *(const bf16x8*)(bb + aRow[m] + aCh[1]);
#pragma unroll
        for (int m = 0; m < 8; ++m)
#pragma unroll
            for (int n = 0; n < 4; ++n)
                acc[m][n] = __builtin_amdgcn_mfma_f32_16x16x32_bf16(af1[m], bf1[n], acc[m][n], 0, 0, 0);

        // 3) convert + swizzled ds_write of next tile (waits only on its loads)
        if (st) {
#pragma unroll
            for (int r = 0; r < 4; ++r) {
                us8 w;
#pragma unroll
                for (int j = 0; j < 4; ++j) { w[j] = f2bf(sa0[r][j]); w[4 + j] = f2bf(sa1[r][j]); }
                *(us8*)(bbn + r * 8192 + t * 16) = w;
            }
#pragma unroll
            for (int r = 0; r < 4; ++r) {
                us8 w;
#pragma unroll
                for (int j = 0; j < 4; ++j) { w[j] = f2bf(sb0[r][j]); w[4 + j] = f2bf(sb1[r][j]); }
                *(us8*)(bbn + 32768 + r * 8192 + t * 16) = w;
            }
        }

        // full drain: all ds_writes landed, all reads done -> next tile safe
        __syncthreads();
        cur ^= 1;
    }

    // epilogue: C/D layout col=lane&15, row=(lane>>4)*4+j; mode is uniform
    const long crow = brow + wr * 128;
    const long ccol = bcol + wc * 64;
#pragma unroll
    for (int m = 0; m < 8; ++m) {
#pragma unroll
        for (int n = 0; n < 4; ++n) {
#pragma unroll
            for (int j = 0; j < 4; ++j) {
                long r = crow + m * 16 + kq * 4 + j;
                long c = ccol + n * 16 + fr;
                float vv = acc[m][n][j];
                if (mode == 0) { vv += bias[c]; C[r * (long)ldc + c] = f2bf(vv); }
                else           { vv += bias[r]; C[r * (long)ldc + c] = f2bf(vv); }
            }
        }
    }
}

// ---------------- 256x256 tile bf16 GEMM, C = A * B^T (R8/R11 proven) ----------------
// MODE 2: fp16 out * scale;  MODE 3: fp32 out.
template <int MODE>
__global__ __launch_bounds__(512, 2) void gemm256d(const u16* __restrict__ A,
                                                   const u16* __restrict__ B,
                                                   void* __restrict__ Cout,
                                                   const float* __restrict__ bias,
                                                   float scale, int K,
                                                   int lda, int ldb, int ldc,
                                                   long sAz, long sBz, long sCz) {
    __shared__ alignas(16) char lds8[2 * 65536];

    const int t    = threadIdx.x;
    const int lane = t & 63;
    const int wid  = t >> 6;
    const int wr   = wid >> 2;    // 0..1
    const int wc   = wid & 3;     // 0..3
    const int fr   = lane & 15;
    const int kq   = lane >> 4;

    const int gx  = gridDim.x;
    const int nwg = gx * gridDim.y;
    const int wg  = blockIdx.y * gx + blockIdx.x;
    const int swz = (wg & 7) * (nwg >> 3) + (wg >> 3);
    const long brow = (long)(swz / gx) * 256;
    const long bcol = (long)(swz % gx) * 256;

    const u16* Az = A + sAz * blockIdx.z;
    const u16* Bz = B + sBz * blockIdx.z;

    const int trow = t >> 3;
    const int tc8  = ((t & 7) ^ (trow & 7)) * 8;
    long offA[4], offB[4];
#pragma unroll
    for (int r = 0; r < 4; ++r) offA[r] = (brow + r * 64 + trow) * (long)lda + tc8;
#pragma unroll
    for (int r = 0; r < 4; ++r) offB[r] = (bcol + r * 64 + trow) * (long)ldb + tc8;

    int aRow[8], bRow[4], aCh[2];
#pragma unroll
    for (int m = 0; m < 8; ++m) aRow[m] = (wr * 128 + m * 16 + fr) * 128;
#pragma unroll
    for (int n = 0; n < 4; ++n) bRow[n] = 32768 + (wc * 64 + n * 16 + fr) * 128;
#pragma unroll
    for (int ks = 0; ks < 2; ++ks) aCh[ks] = (((ks << 2) | kq) ^ (fr & 7)) * 16;

    const int NT = K >> 6;
    f32x4 acc[8][4] = {};

    {
        char* bb0 = lds8;
#pragma unroll
        for (int r = 0; r < 4; ++r)
            __builtin_amdgcn_global_load_lds((const AS1 unsigned*)(Az + offA[r]),
                                             (AS3 unsigned*)(bb0 + r * 8192 + t * 16), 16, 0, 0);
#pragma unroll
        for (int r = 0; r < 4; ++r)
            __builtin_amdgcn_global_load_lds((const AS1 unsigned*)(Bz + offB[r]),
                                             (AS3 unsigned*)(bb0 + 32768 + r * 8192 + t * 16), 16, 0, 0);
    }
    __syncthreads();

    int cur = 0;
    for (int T = 0; T < NT; ++T) {
        char* bb  = lds8 + cur * 65536;
        char* bbn = lds8 + (cur ^ 1) * 65536;

        if (T + 1 < NT) {
            const long kcol = (long)(T + 1) << 6;
#pragma unroll
            for (int r = 0; r < 4; ++r)
                __builtin_amdgcn_global_load_lds((const AS1 unsigned*)(Az + offA[r] + kcol),
                                                 (AS3 unsigned*)(bbn + r * 8192 + t * 16), 16, 0, 0);
#pragma unroll
            for (int r = 0; r < 4; ++r)
                __builtin_amdgcn_global_load_lds((const AS1 unsigned*)(Bz + offB[r] + kcol),
                                                 (AS3 unsigned*)(bbn + 32768 + r * 8192 + t * 16), 16, 0, 0);
        }

        bf16x8 af0[8], bf0[4], af1[8], bf1[4];
#pragma unroll
        for (int n = 0; n < 4; ++n) bf0[n] = *(const bf16x8*)(bb + bRow[n] + aCh[0]);
#pragma unroll
        for (int m = 0; m < 8; ++m) af0[m] = *(const bf16x8*)(bb + aRow[m] + aCh[0]);

#pragma unroll
        for (int m = 0; m < 8; ++m)
#pragma unroll
            for (int n = 0; n < 4; ++n)
                acc[m][n] = __builtin_amdgcn_mfma_f32_16x16x32_bf16(af0[m], bf0[n], acc[m][n], 0, 0, 0);

#pragma unroll
        for (int n = 0; n < 4; ++n) bf1[n] = *(const bf16x8*)(bb + bRow[n] + aCh[1]);
#pragma unroll
        for (int m = 0; m < 8; ++m) af1[m] = *(const bf16x8*)(bb + aRow[m] + aCh[1]);

#pragma unroll
        for (int m = 0; m < 8; ++m)
#pragma unroll
            for (int n = 0; n < 4; ++n)
                acc[m][n] = __builtin_amdgcn_mfma_f32_16x16x32_bf16(af1[m], bf1[n], acc[m][n], 0, 0, 0);

        __syncthreads();
        cur ^= 1;
    }

    const long crow = brow + wr * 128;
    const long ccol = bcol + wc * 64;
    const long cz = sCz * blockIdx.z;
#pragma unroll
    for (int m = 0; m < 8; ++m) {
#pragma unroll
        for (int n = 0; n < 4; ++n) {
#pragma unroll
            for (int j = 0; j < 4; ++j) {
                long r = crow + m * 16 + kq * 4 + j;
                long c = ccol + n * 16 + fr;
                float vv = acc[m][n][j];
                if (MODE == 0)      { vv += bias[c]; ((u16*)Cout)[cz + r * ldc + c] = f2bf(vv); }
                else if (MODE == 1) { vv += bias[r]; ((u16*)Cout)[cz + r * ldc + c] = f2bf(vv); }
                else if (MODE == 2) { ((_Float16*)Cout)[cz + r * ldc + c] = (_Float16)(vv * scale); }
                else                { ((float*)Cout)[cz + r * ldc + c] = vv; }
            }
        }
    }
}

// ---------------- row softmax: fp16 in -> bf16 out, in place, L=4096 ----------------
__global__ __launch_bounds__(256) void softmax_row(u16* __restrict__ S, int L) {
    const long row = blockIdx.x;
    u16* rp = S + row * L;
    const int t = threadIdx.x;
    const int lane = t & 63, wid = t >> 6;

    f16x8 h0 = *(const f16x8*)(rp + t * 16);
    f16x8 h1 = *(const f16x8*)(rp + t * 16 + 8);
    float x[16];
#pragma unroll
    for (int j = 0; j < 8; ++j) { x[j] = (float)h0[j]; x[8 + j] = (float)h1[j]; }

    float m = -1e30f;
#pragma unroll
    for (int j = 0; j < 16; ++j) m = fmaxf(m, x[j]);
#pragma unroll
    for (int o = 32; o; o >>= 1) m = fmaxf(m, __shfl_xor(m, o));

    __shared__ float redmax[4], redsum[4];
    if (lane == 0) redmax[wid] = m;
    __syncthreads();
    m = fmaxf(fmaxf(redmax[0], redmax[1]), fmaxf(redmax[2], redmax[3]));

    float e[16], s = 0.f;
#pragma unroll
    for (int j = 0; j < 16; ++j) { e[j] = __expf(x[j] - m); s += e[j]; }
#pragma unroll
    for (int o = 32; o; o >>= 1) s += __shfl_xor(s, o);
    if (lane == 0) redsum[wid] = s;
    __syncthreads();
    s = redsum[0] + redsum[1] + redsum[2] + redsum[3];
    float inv = 1.f / s;

    us8 o0, o1;
#pragma unroll
    for (int j = 0; j < 8; ++j) { o0[j] = f2bf(e[j] * inv); o1[j] = f2bf(e[8 + j] * inv); }
    *(us8*)(rp + t * 16) = o0;
    *(us8*)(rp + t * 16 + 8) = o1;
}

extern "C" void kernel_launch(void* const* d_in, const int* in_sizes, int n_in,
                              void* d_out, int out_size, void* d_ws, size_t ws_size,
                              hipStream_t stream) {
    (void)in_sizes; (void)n_in; (void)out_size;
    const float* q  = (const float*)d_in[0];
    const float* k  = (const float*)d_in[1];
    const float* v  = (const float*)d_in[2];
    const float* Wq = (const float*)d_in[3];
    const float* bq = (const float*)d_in[4];
    const float* Wk = (const float*)d_in[5];
    const float* bk = (const float*)d_in[6];
    const float* Wv = (const float*)d_in[7];
    const float* bv = (const float*)d_in[8];
    float* out = (float*)d_out;

    constexpr long MB = 1l << 20;
    char* ws = (char*)d_ws;
    u16* pq  = (u16*)(ws + 0 * MB);     // 32 MB  [16384,1024] bf16
    u16* pk  = (u16*)(ws + 32 * MB);    // 32 MB
    u16* pvT = (u16*)(ws + 64 * MB);    // 32 MB  [1024,16384] bf16
    u16* S4  = (u16*)(ws + 96 * MB);    // z4: 128 MB (96..224)

    const int L = 4096, E = 1024, NB = 4;
    const bool z4 = ws_size >= (size_t)225 * MB;

    // fused cast + projections, one dispatch (768 blocks)
    proj3f<<<dim3(256, 3), 512, 0, stream>>>(q, k, v, Wq, Wk, Wv,
                                             pq, pk, pvT, bq, bk, bv, E, NB * L);

    const float scale = 0.03125f;  // 1/sqrt(1024)
    if (z4) {
        // S (fp16), all 4 batches: 1024 blocks
        gemm256d<2><<<dim3(16, 16, 4), 512, 0, stream>>>(pq, pk, S4, nullptr, scale, E, E, E, L,
                                                         (long)L * E, (long)L * E, (long)L * L);
        softmax_row<<<NB * L, 256, 0, stream>>>(S4, L);
        // PV: out = attn @ pvT^T (256 blocks)
        gemm256d<3><<<dim3(4, 16, 4), 512, 0, stream>>>(S4, pvT, out,
                                                        nullptr, 1.f, L, L, NB * L, E,
                                                        (long)L * L, (long)L, (long)L * E);
    } else {
        u16* S2 = S4;  // 64 MB, 2 batches at a time
        for (int p = 0; p < 2; ++p) {
            const long zb = p * 2;
            gemm256d<2><<<dim3(16, 16, 2), 512, 0, stream>>>(pq + zb * L * E, pk + zb * L * E,
                                                             S2, nullptr, scale, E, E, E, L,
                                                             (long)L * E, (long)L * E, (long)L * L);
            softmax_row<<<2 * L, 256, 0, stream>>>(S2, L);
            gemm256d<3><<<dim3(4, 16, 2), 512, 0, stream>>>(S2, pvT + zb * L, out + zb * L * E,
                                                            nullptr, 1.f, L, L, NB * L, E,
                                                            (long)L * L, (long)L, (long)L * E);
        }
    }
}

// Round 16
// 477.628 us; speedup vs baseline: 1.0032x; 1.0032x over previous
//
#include <hip/hip_runtime.h>

typedef unsigned short u16;
typedef __bf16  bf16x8 __attribute__((ext_vector_type(8)));
typedef float   f32x4  __attribute__((ext_vector_type(4)));
typedef unsigned short us8 __attribute__((ext_vector_type(8)));
typedef _Float16 f16x8 __attribute__((ext_vector_type(8)));
typedef float   fl4   __attribute__((ext_vector_type(4)));

#define AS1 __attribute__((address_space(1)))
#define AS3 __attribute__((address_space(3)))

__device__ __forceinline__ u16 f2bf(float f) {
    union { float f; unsigned u; } x; x.f = f;
    unsigned r = x.u + 0x7fffu + ((x.u >> 16) & 1u);
    return (u16)(r >> 16);
}

// ---------------- fused fp32->bf16 projections, all 3 in ONE dispatch ----------------
// C = A(fp32) * B(fp32)^T + bias, output bf16. Register-staging replaces
// global_load_lds: per K-tile, 16 global fl4-pair loads -> in-reg f2bf ->
// swizzled ds_write_b128 (same physical LDS layout as the DMA path, so the
// proven frag-read side is byte-identical). Drain-all __syncthreads covers
// ds_writes + reads -> race-free by construction. blockIdx.y routes
// {pq, pk, pvT}; eliminates the separate cast kernel entirely.
__global__ __launch_bounds__(512, 2) void proj3f(const float* __restrict__ q,
                                                 const float* __restrict__ k,
                                                 const float* __restrict__ v,
                                                 const float* __restrict__ Wq,
                                                 const float* __restrict__ Wk,
                                                 const float* __restrict__ Wv,
                                                 u16* __restrict__ pq, u16* __restrict__ pk,
                                                 u16* __restrict__ pvT,
                                                 const float* __restrict__ bq,
                                                 const float* __restrict__ bk,
                                                 const float* __restrict__ bv,
                                                 int E, int NBL) {
    __shared__ alignas(16) char lds8[2 * 65536];

    const int t    = threadIdx.x;
    const int lane = t & 63;
    const int wid  = t >> 6;
    const int wr   = wid >> 2;    // 0..1
    const int wc   = wid & 3;     // 0..3
    const int fr   = lane & 15;
    const int kq   = lane >> 4;

    // route the three sub-GEMMs
    const int y  = blockIdx.y;
    const int bx = blockIdx.x;                  // 0..255
    const int swz = (bx & 7) * 32 + (bx >> 3);  // XCD-bijective (256%8==0)
    const float *A, *B, *bias; u16* C; int ldc, tx, ty, mode;
    if (y < 2) {   // pq/pk = x @ W^T + b[col]: M=16384 (ty 0..63), N=1024 (tx 0..3)
        A = y ? k : q; B = y ? Wk : Wq; C = y ? pk : pq; bias = y ? bk : bq;
        ldc = E; tx = swz & 3; ty = swz >> 2; mode = 0;
    } else {       // pvT = Wv @ v^T + bv[row]: M=1024 (ty 0..3), N=16384 (tx 0..63)
        A = Wv; B = v; C = pvT; bias = bv;
        ldc = NBL; tx = swz & 63; ty = swz >> 6; mode = 1;
    }
    const long brow = (long)ty * 256;
    const long bcol = (long)tx * 256;

    // staging geometry: round r covers rows r*64+(t>>3); logical chunk
    // Lc=(t&7)^(row&7) pre-swizzled into the SOURCE; phys dest = r*8192+t*16.
    const int trow = t >> 3;
    const int Lc8  = ((t & 7) ^ (trow & 7)) * 8;   // fp32 element offset
    long offA[4], offB[4];
#pragma unroll
    for (int r = 0; r < 4; ++r) offA[r] = (brow + r * 64 + trow) * (long)E + Lc8;
#pragma unroll
    for (int r = 0; r < 4; ++r) offB[r] = (bcol + r * 64 + trow) * (long)E + Lc8;

    // frag read offsets (identical to gemm256d)
    int aRow[8], bRow[4], aCh[2];
#pragma unroll
    for (int m = 0; m < 8; ++m) aRow[m] = (wr * 128 + m * 16 + fr) * 128;
#pragma unroll
    for (int n = 0; n < 4; ++n) bRow[n] = 32768 + (wc * 64 + n * 16 + fr) * 128;
#pragma unroll
    for (int ks = 0; ks < 2; ++ks) aCh[ks] = (((ks << 2) | kq) ^ (fr & 7)) * 16;

    const int NT = E >> 6;   // 16
    f32x4 acc[8][4] = {};

    // prologue: reg-stage tile 0 into buffer 0
    {
#pragma unroll
        for (int r = 0; r < 4; ++r) {
            const float* pA = A + offA[r];
            fl4 a0 = *(const fl4*)pA, a1 = *(const fl4*)(pA + 4);
            us8 w;
#pragma unroll
            for (int j = 0; j < 4; ++j) { w[j] = f2bf(a0[j]); w[4 + j] = f2bf(a1[j]); }
            *(us8*)(lds8 + r * 8192 + t * 16) = w;
        }
#pragma unroll
        for (int r = 0; r < 4; ++r) {
            const float* pB = B + offB[r];
            fl4 b0 = *(const fl4*)pB, b1 = *(const fl4*)(pB + 4);
            us8 w;
#pragma unroll
            for (int j = 0; j < 4; ++j) { w[j] = f2bf(b0[j]); w[4 + j] = f2bf(b1[j]); }
            *(us8*)(lds8 + 32768 + r * 8192 + t * 16) = w;
        }
    }
    __syncthreads();

    int cur = 0;
    for (int T = 0; T < NT; ++T) {
        char* bb  = lds8 + cur * 65536;
        char* bbn = lds8 + (cur ^ 1) * 65536;
        const bool st = (T + 1) < NT;

        // 1) issue next tile's global loads into named regs (latency hides
        //    under the frag-read + MFMA section below)
        fl4 sa0[4], sa1[4], sb0[4], sb1[4];
        if (st) {
            const long kc = (long)(T + 1) << 6;
#pragma unroll
            for (int r = 0; r < 4; ++r) {
                const float* pA = A + offA[r] + kc;
                sa0[r] = *(const fl4*)pA; sa1[r] = *(const fl4*)(pA + 4);
                const float* pB = B + offB[r] + kc;
                sb0[r] = *(const fl4*)pB; sb1[r] = *(const fl4*)(pB + 4);
            }
        }

        // 2) frag reads + MFMAs (two ksub phases, disjoint frag regs)
        bf16x8 af0[8], bf0[4], af1[8], bf1[4];
#pragma unroll
        for (int n = 0; n < 4; ++n) bf0[n] = *(const bf16x8*)(bb + bRow[n] + aCh[0]);
#pragma unroll
        for (int m = 0; m < 8; ++m) af0[m] = *(const bf16x8*)(bb + aRow[m] + aCh[0]);
#pragma unroll
        for (int m = 0; m < 8; ++m)
#pragma unroll
            for (int n = 0; n < 4; ++n)
                acc[m][n] = __builtin_amdgcn_mfma_f32_16x16x32_bf16(af0[m], bf0[n], acc[m][n], 0, 0, 0);

#pragma unroll
        for (int n = 0; n < 4; ++n) bf1[n] = *(const bf16x8*)(bb + bRow[n] + aCh[1]);
#pragma unroll
        for (int m = 0; m < 8; ++m) af1[m] = *(const bf16x8*)(bb + aRow[m] + aCh[1]);
#pragma unroll
        for (int m = 0; m < 8; ++m)
#pragma unroll
            for (int n = 0; n < 4; ++n)
                acc[m][n] = __builtin_amdgcn_mfma_f32_16x16x32_bf16(af1[m], bf1[n], acc[m][n], 0, 0, 0);

        // 3) convert + swizzled ds_write of next tile (waits only on its loads)
        if (st) {
#pragma unroll
            for (int r = 0; r < 4; ++r) {
                us8 w;
#pragma unroll
                for (int j = 0; j < 4; ++j) { w[j] = f2bf(sa0[r][j]); w[4 + j] = f2bf(sa1[r][j]); }
                *(us8*)(bbn + r * 8192 + t * 16) = w;
            }
#pragma unroll
            for (int r = 0; r < 4; ++r) {
                us8 w;
#pragma unroll
                for (int j = 0; j < 4; ++j) { w[j] = f2bf(sb0[r][j]); w[4 + j] = f2bf(sb1[r][j]); }
                *(us8*)(bbn + 32768 + r * 8192 + t * 16) = w;
            }
        }

        // full drain: all ds_writes landed, all reads done -> next tile safe
        __syncthreads();
        cur ^= 1;
    }

    // epilogue: C/D layout col=lane&15, row=(lane>>4)*4+j; mode is uniform
    const long crow = brow + wr * 128;
    const long ccol = bcol + wc * 64;
#pragma unroll
    for (int m = 0; m < 8; ++m) {
#pragma unroll
        for (int n = 0; n < 4; ++n) {
#pragma unroll
            for (int j = 0; j < 4; ++j) {
                long r = crow + m * 16 + kq * 4 + j;
                long c = ccol + n * 16 + fr;
                float vv = acc[m][n][j];
                if (mode == 0) { vv += bias[c]; C[r * (long)ldc + c] = f2bf(vv); }
                else           { vv += bias[r]; C[r * (long)ldc + c] = f2bf(vv); }
            }
        }
    }
}

// ---------------- 256x256 tile bf16 GEMM, C = A * B^T (R8/R11 proven) ----------------
// MODE 2: fp16 out * scale;  MODE 3: fp32 out.
template <int MODE>
__global__ __launch_bounds__(512, 2) void gemm256d(const u16* __restrict__ A,
                                                   const u16* __restrict__ B,
                                                   void* __restrict__ Cout,
                                                   const float* __restrict__ bias,
                                                   float scale, int K,
                                                   int lda, int ldb, int ldc,
                                                   long sAz, long sBz, long sCz) {
    __shared__ alignas(16) char lds8[2 * 65536];

    const int t    = threadIdx.x;
    const int lane = t & 63;
    const int wid  = t >> 6;
    const int wr   = wid >> 2;    // 0..1
    const int wc   = wid & 3;     // 0..3
    const int fr   = lane & 15;
    const int kq   = lane >> 4;

    const int gx  = gridDim.x;
    const int nwg = gx * gridDim.y;
    const int wg  = blockIdx.y * gx + blockIdx.x;
    const int swz = (wg & 7) * (nwg >> 3) + (wg >> 3);
    const long brow = (long)(swz / gx) * 256;
    const long bcol = (long)(swz % gx) * 256;

    const u16* Az = A + sAz * blockIdx.z;
    const u16* Bz = B + sBz * blockIdx.z;

    const int trow = t >> 3;
    const int tc8  = ((t & 7) ^ (trow & 7)) * 8;
    long offA[4], offB[4];
#pragma unroll
    for (int r = 0; r < 4; ++r) offA[r] = (brow + r * 64 + trow) * (long)lda + tc8;
#pragma unroll
    for (int r = 0; r < 4; ++r) offB[r] = (bcol + r * 64 + trow) * (long)ldb + tc8;

    int aRow[8], bRow[4], aCh[2];
#pragma unroll
    for (int m = 0; m < 8; ++m) aRow[m] = (wr * 128 + m * 16 + fr) * 128;
#pragma unroll
    for (int n = 0; n < 4; ++n) bRow[n] = 32768 + (wc * 64 + n * 16 + fr) * 128;
#pragma unroll
    for (int ks = 0; ks < 2; ++ks) aCh[ks] = (((ks << 2) | kq) ^ (fr & 7)) * 16;

    const int NT = K >> 6;
    f32x4 acc[8][4] = {};

    {
        char* bb0 = lds8;
#pragma unroll
        for (int r = 0; r < 4; ++r)
            __builtin_amdgcn_global_load_lds((const AS1 unsigned*)(Az + offA[r]),
                                             (AS3 unsigned*)(bb0 + r * 8192 + t * 16), 16, 0, 0);
#pragma unroll
        for (int r = 0; r < 4; ++r)
            __builtin_amdgcn_global_load_lds((const AS1 unsigned*)(Bz + offB[r]),
                                             (AS3 unsigned*)(bb0 + 32768 + r * 8192 + t * 16), 16, 0, 0);
    }
    __syncthreads();

    int cur = 0;
    for (int T = 0; T < NT; ++T) {
        char* bb  = lds8 + cur * 65536;
        char* bbn = lds8 + (cur ^ 1) * 65536;

        if (T + 1 < NT) {
            const long kcol = (long)(T + 1) << 6;
#pragma unroll
            for (int r = 0; r < 4; ++r)
                __builtin_amdgcn_global_load_lds((const AS1 unsigned*)(Az + offA[r] + kcol),
                                                 (AS3 unsigned*)(bbn + r * 8192 + t * 16), 16, 0, 0);
#pragma unroll
            for (int r = 0; r < 4; ++r)
                __builtin_amdgcn_global_load_lds((const AS1 unsigned*)(Bz + offB[r] + kcol),
                                                 (AS3 unsigned*)(bbn + 32768 + r * 8192 + t * 16), 16, 0, 0);
        }

        bf16x8 af0[8], bf0[4], af1[8], bf1[4];
#pragma unroll
        for (int n = 0; n < 4; ++n) bf0[n] = *(const bf16x8*)(bb + bRow[n] + aCh[0]);
#pragma unroll
        for (int m = 0; m < 8; ++m) af0[m] = *(const bf16x8*)(bb + aRow[m] + aCh[0]);

#pragma unroll
        for (int m = 0; m < 8; ++m)
#pragma unroll
            for (int n = 0; n < 4; ++n)
                acc[m][n] = __builtin_amdgcn_mfma_f32_16x16x32_bf16(af0[m], bf0[n], acc[m][n], 0, 0, 0);

#pragma unroll
        for (int n = 0; n < 4; ++n) bf1[n] = *(const bf16x8*)(bb + bRow[n] + aCh[1]);
#pragma unroll
        for (int m = 0; m < 8; ++m) af1[m] = *(const bf16x8*)(bb + aRow[m] + aCh[1]);

#pragma unroll
        for (int m = 0; m < 8; ++m)
#pragma unroll
            for (int n = 0; n < 4; ++n)
                acc[m][n] = __builtin_amdgcn_mfma_f32_16x16x32_bf16(af1[m], bf1[n], acc[m][n], 0, 0, 0);

        __syncthreads();
        cur ^= 1;
    }

    const long crow = brow + wr * 128;
    const long ccol = bcol + wc * 64;
    const long cz = sCz * blockIdx.z;
#pragma unroll
    for (int m = 0; m < 8; ++m) {
#pragma unroll
        for (int n = 0; n < 4; ++n) {
#pragma unroll
            for (int j = 0; j < 4; ++j) {
                long r = crow + m * 16 + kq * 4 + j;
                long c = ccol + n * 16 + fr;
                float vv = acc[m][n][j];
                if (MODE == 0)      { vv += bias[c]; ((u16*)Cout)[cz + r * ldc + c] = f2bf(vv); }
                else if (MODE == 1) { vv += bias[r]; ((u16*)Cout)[cz + r * ldc + c] = f2bf(vv); }
                else if (MODE == 2) { ((_Float16*)Cout)[cz + r * ldc + c] = (_Float16)(vv * scale); }
                else                { ((float*)Cout)[cz + r * ldc + c] = vv; }
            }
        }
    }
}

// ---------------- row softmax: fp16 in -> bf16 out, in place, L=4096 ----------------
__global__ __launch_bounds__(256) void softmax_row(u16* __restrict__ S, int L) {
    const long row = blockIdx.x;
    u16* rp = S + row * L;
    const int t = threadIdx.x;
    const int lane = t & 63, wid = t >> 6;

    f16x8 h0 = *(const f16x8*)(rp + t * 16);
    f16x8 h1 = *(const f16x8*)(rp + t * 16 + 8);
    float x[16];
#pragma unroll
    for (int j = 0; j < 8; ++j) { x[j] = (float)h0[j]; x[8 + j] = (float)h1[j]; }

    float m = -1e30f;
#pragma unroll
    for (int j = 0; j < 16; ++j) m = fmaxf(m, x[j]);
#pragma unroll
    for (int o = 32; o; o >>= 1) m = fmaxf(m, __shfl_xor(m, o));

    __shared__ float redmax[4], redsum[4];
    if (lane == 0) redmax[wid] = m;
    __syncthreads();
    m = fmaxf(fmaxf(redmax[0], redmax[1]), fmaxf(redmax[2], redmax[3]));

    float e[16], s = 0.f;
#pragma unroll
    for (int j = 0; j < 16; ++j) { e[j] = __expf(x[j] - m); s += e[j]; }
#pragma unroll
    for (int o = 32; o; o >>= 1) s += __shfl_xor(s, o);
    if (lane == 0) redsum[wid] = s;
    __syncthreads();
    s = redsum[0] + redsum[1] + redsum[2] + redsum[3];
    float inv = 1.f / s;

    us8 o0, o1;
#pragma unroll
    for (int j = 0; j < 8; ++j) { o0[j] = f2bf(e[j] * inv); o1[j] = f2bf(e[8 + j] * inv); }
    *(us8*)(rp + t * 16) = o0;
    *(us8*)(rp + t * 16 + 8) = o1;
}

extern "C" void kernel_launch(void* const* d_in, const int* in_sizes, int n_in,
                              void* d_out, int out_size, void* d_ws, size_t ws_size,
                              hipStream_t stream) {
    (void)in_sizes; (void)n_in; (void)out_size;
    const float* q  = (const float*)d_in[0];
    const float* k  = (const float*)d_in[1];
    const float* v  = (const float*)d_in[2];
    const float* Wq = (const float*)d_in[3];
    const float* bq = (const float*)d_in[4];
    const float* Wk = (const float*)d_in[5];
    const float* bk = (const float*)d_in[6];
    const float* Wv = (const float*)d_in[7];
    const float* bv = (const float*)d_in[8];
    float* out = (float*)d_out;

    constexpr long MB = 1l << 20;
    char* ws = (char*)d_ws;
    u16* pq  = (u16*)(ws + 0 * MB);     // 32 MB  [16384,1024] bf16
    u16* pk  = (u16*)(ws + 32 * MB);    // 32 MB
    u16* pvT = (u16*)(ws + 64 * MB);    // 32 MB  [1024,16384] bf16
    u16* S4  = (u16*)(ws + 96 * MB);    // z4: 128 MB (96..224)

    const int L = 4096, E = 1024, NB = 4;
    const bool z4 = ws_size >= (size_t)225 * MB;

    // fused cast + projections, one dispatch (768 blocks)
    proj3f<<<dim3(256, 3), 512, 0, stream>>>(q, k, v, Wq, Wk, Wv,
                                             pq, pk, pvT, bq, bk, bv, E, NB * L);

    const float scale = 0.03125f;  // 1/sqrt(1024)
    if (z4) {
        // S (fp16), all 4 batches: 1024 blocks
        gemm256d<2><<<dim3(16, 16, 4), 512, 0, stream>>>(pq, pk, S4, nullptr, scale, E, E, E, L,
                                                         (long)L * E, (long)L * E, (long)L * L);
        softmax_row<<<NB * L, 256, 0, stream>>>(S4, L);
        // PV: out = attn @ pvT^T (256 blocks)
        gemm256d<3><<<dim3(4, 16, 4), 512, 0, stream>>>(S4, pvT, out,
                                                        nullptr, 1.f, L, L, NB * L, E,
                                                        (long)L * L, (long)L, (long)L * E);
    } else {
        u16* S2 = S4;  // 64 MB, 2 batches at a time
        for (int p = 0; p < 2; ++p) {
            const long zb = p * 2;
            gemm256d<2><<<dim3(16, 16, 2), 512, 0, stream>>>(pq + zb * L * E, pk + zb * L * E,
                                                             S2, nullptr, scale, E, E, E, L,
                                                             (long)L * E, (long)L * E, (long)L * L);
            softmax_row<<<2 * L, 256, 0, stream>>>(S2, L);
            gemm256d<3><<<dim3(4, 16, 2), 512, 0, stream>>>(S2, pvT + zb * L, out + zb * L * E,
                                                            nullptr, 1.f, L, L, NB * L, E,
                                                            (long)L * L, (long)L, (long)L * E);
        }
    }
}

// Round 17
// 404.273 us; speedup vs baseline: 1.1852x; 1.1814x over previous
//
#include <hip/hip_runtime.h>

typedef unsigned short u16;
typedef __bf16  bf16x8 __attribute__((ext_vector_type(8)));
typedef float   f32x4  __attribute__((ext_vector_type(4)));
typedef unsigned short us8 __attribute__((ext_vector_type(8)));
typedef float   fl4   __attribute__((ext_vector_type(4)));

#define AS1 __attribute__((address_space(1)))
#define AS3 __attribute__((address_space(3)))

__device__ __forceinline__ u16 f2bf(float f) {
    union { float f; unsigned u; } x; x.f = f;
    unsigned r = x.u + 0x7fffu + ((x.u >> 16) & 1u);
    return (u16)(r >> 16);
}

// ---------------- fp32 -> bf16 cast, 6 tensors in one dispatch ----------------
__global__ __launch_bounds__(256) void cvt6(const float* __restrict__ q,
                                            const float* __restrict__ k,
                                            const float* __restrict__ v,
                                            const float* __restrict__ Wq,
                                            const float* __restrict__ Wk,
                                            const float* __restrict__ Wv,
                                            u16* __restrict__ qb, u16* __restrict__ kb,
                                            u16* __restrict__ vb, u16* __restrict__ Wqb,
                                            u16* __restrict__ Wkb, u16* __restrict__ Wvb,
                                            int n8x, int n8w) {
    const int y = blockIdx.y;
    const float* in; u16* out; int n8;
    switch (y) {
        case 0: in = q;  out = qb;  n8 = n8x; break;
        case 1: in = k;  out = kb;  n8 = n8x; break;
        case 2: in = v;  out = vb;  n8 = n8x; break;
        case 3: in = Wq; out = Wqb; n8 = n8w; break;
        case 4: in = Wk; out = Wkb; n8 = n8w; break;
        default: in = Wv; out = Wvb; n8 = n8w; break;
    }
    int i = blockIdx.x * blockDim.x + threadIdx.x;
    int stride = gridDim.x * blockDim.x;
    for (; i < n8; i += stride) {
        const fl4* p = (const fl4*)(in + (long)i * 8);
        fl4 a = p[0], b = p[1];
        us8 o;
#pragma unroll
        for (int j = 0; j < 4; ++j) { o[j] = f2bf(a[j]); o[4 + j] = f2bf(b[j]); }
        *(us8*)(out + (long)i * 8) = o;
    }
}

// ---------------- 256x256 tile bf16 GEMM core (R10 proven schedule) ----------------
// Drain-all: stage T+1 first (DMA), plain-C++ ds_reads, MFMA, one __syncthreads
// per K-tile. Epilogue MODEs:
//  0: bf16 out + bias[col]            (pq/pk projection)
//  1: bf16 out + bias[row]            (pvT projection)
//  4: bf16 out = exp(v*scale), per-row partial sums -> aux[p*nrows + grow0+r]
//  5: fp32 out = v * aux[grow0+r]     (PV with 1/rowsum)
template <int MODE>
__device__ __forceinline__ void gcore(char* lds8,
                                      const u16* __restrict__ A,
                                      const u16* __restrict__ B,
                                      void* __restrict__ Cout,
                                      const float* __restrict__ bias,
                                      float* __restrict__ aux,
                                      float scale, int K,
                                      int lda, int ldb, int ldc,
                                      int tx, int ty, long grow0, int nrows) {
    const int t    = threadIdx.x;
    const int lane = t & 63;
    const int wid  = t >> 6;
    const int wr   = wid >> 2;    // 0..1
    const int wc   = wid & 3;     // 0..3
    const int fr   = lane & 15;
    const int kq   = lane >> 4;

    const long brow = (long)ty * 256;
    const long bcol = (long)tx * 256;

    const int trow = t >> 3;
    const int tc8  = ((t & 7) ^ (trow & 7)) * 8;
    long offA[4], offB[4];
#pragma unroll
    for (int r = 0; r < 4; ++r) offA[r] = (brow + r * 64 + trow) * (long)lda + tc8;
#pragma unroll
    for (int r = 0; r < 4; ++r) offB[r] = (bcol + r * 64 + trow) * (long)ldb + tc8;

    int aRow[8], bRow[4], aCh[2];
#pragma unroll
    for (int m = 0; m < 8; ++m) aRow[m] = (wr * 128 + m * 16 + fr) * 128;
#pragma unroll
    for (int n = 0; n < 4; ++n) bRow[n] = 32768 + (wc * 64 + n * 16 + fr) * 128;
#pragma unroll
    for (int ks = 0; ks < 2; ++ks) aCh[ks] = (((ks << 2) | kq) ^ (fr & 7)) * 16;

    const int NT = K >> 6;
    f32x4 acc[8][4] = {};

    {
#pragma unroll
        for (int r = 0; r < 4; ++r)
            __builtin_amdgcn_global_load_lds((const AS1 unsigned*)(A + offA[r]),
                                             (AS3 unsigned*)(lds8 + r * 8192 + t * 16), 16, 0, 0);
#pragma unroll
        for (int r = 0; r < 4; ++r)
            __builtin_amdgcn_global_load_lds((const AS1 unsigned*)(B + offB[r]),
                                             (AS3 unsigned*)(lds8 + 32768 + r * 8192 + t * 16), 16, 0, 0);
    }
    __syncthreads();

    int cur = 0;
    for (int T = 0; T < NT; ++T) {
        char* bb  = lds8 + cur * 65536;
        char* bbn = lds8 + (cur ^ 1) * 65536;

        if (T + 1 < NT) {
            const long kcol = (long)(T + 1) << 6;
#pragma unroll
            for (int r = 0; r < 4; ++r)
                __builtin_amdgcn_global_load_lds((const AS1 unsigned*)(A + offA[r] + kcol),
                                                 (AS3 unsigned*)(bbn + r * 8192 + t * 16), 16, 0, 0);
#pragma unroll
            for (int r = 0; r < 4; ++r)
                __builtin_amdgcn_global_load_lds((const AS1 unsigned*)(B + offB[r] + kcol),
                                                 (AS3 unsigned*)(bbn + 32768 + r * 8192 + t * 16), 16, 0, 0);
        }

        bf16x8 af0[8], bf0[4], af1[8], bf1[4];
#pragma unroll
        for (int n = 0; n < 4; ++n) bf0[n] = *(const bf16x8*)(bb + bRow[n] + aCh[0]);
#pragma unroll
        for (int m = 0; m < 8; ++m) af0[m] = *(const bf16x8*)(bb + aRow[m] + aCh[0]);

#pragma unroll
        for (int m = 0; m < 8; ++m)
#pragma unroll
            for (int n = 0; n < 4; ++n)
                acc[m][n] = __builtin_amdgcn_mfma_f32_16x16x32_bf16(af0[m], bf0[n], acc[m][n], 0, 0, 0);

#pragma unroll
        for (int n = 0; n < 4; ++n) bf1[n] = *(const bf16x8*)(bb + bRow[n] + aCh[1]);
#pragma unroll
        for (int m = 0; m < 8; ++m) af1[m] = *(const bf16x8*)(bb + aRow[m] + aCh[1]);

#pragma unroll
        for (int m = 0; m < 8; ++m)
#pragma unroll
            for (int n = 0; n < 4; ++n)
                acc[m][n] = __builtin_amdgcn_mfma_f32_16x16x32_bf16(af1[m], bf1[n], acc[m][n], 0, 0, 0);

        __syncthreads();
        cur ^= 1;
    }

    // epilogue: C/D layout col=lane&15, row=(lane>>4)*4+j
    const long crow = brow + wr * 128;
    const long ccol = bcol + wc * 64;
    if (MODE == 0 || MODE == 1) {
#pragma unroll
        for (int m = 0; m < 8; ++m)
#pragma unroll
            for (int n = 0; n < 4; ++n)
#pragma unroll
                for (int j = 0; j < 4; ++j) {
                    long r = crow + m * 16 + kq * 4 + j;
                    long c = ccol + n * 16 + fr;
                    float vv = acc[m][n][j] + (MODE == 0 ? bias[c] : bias[r]);
                    ((u16*)Cout)[r * (long)ldc + c] = f2bf(vv);
                }
    } else if (MODE == 4) {
        const int p = tx * 4 + wc;
#pragma unroll
        for (int m = 0; m < 8; ++m)
#pragma unroll
            for (int j = 0; j < 4; ++j) {
                long r = crow + m * 16 + kq * 4 + j;
                float rs = 0.f;
#pragma unroll
                for (int n = 0; n < 4; ++n) {
                    float e = __expf(acc[m][n][j] * scale);
                    ((u16*)Cout)[r * (long)ldc + (ccol + n * 16 + fr)] = f2bf(e);
                    rs += e;
                }
                rs += __shfl_xor(rs, 1);
                rs += __shfl_xor(rs, 2);
                rs += __shfl_xor(rs, 4);
                rs += __shfl_xor(rs, 8);
                if (fr == 0) aux[(long)p * nrows + grow0 + r] = rs;
            }
    } else {  // MODE 5
#pragma unroll
        for (int m = 0; m < 8; ++m)
#pragma unroll
            for (int j = 0; j < 4; ++j) {
                long r = crow + m * 16 + kq * 4 + j;
                float rinv = aux[grow0 + r];
#pragma unroll
                for (int n = 0; n < 4; ++n)
                    ((float*)Cout)[r * (long)ldc + (ccol + n * 16 + fr)] = acc[m][n][j] * rinv;
            }
    }
}

// ---------------- all 3 projections in one dispatch (proven DMA body) ----------------
__global__ __launch_bounds__(512, 2) void proj3(const u16* __restrict__ qb,
                                                const u16* __restrict__ kb,
                                                const u16* __restrict__ vb,
                                                const u16* __restrict__ Wqb,
                                                const u16* __restrict__ Wkb,
                                                const u16* __restrict__ Wvb,
                                                u16* __restrict__ pq, u16* __restrict__ pk,
                                                u16* __restrict__ pvT,
                                                const float* __restrict__ bq,
                                                const float* __restrict__ bk,
                                                const float* __restrict__ bv,
                                                int E, int NBL) {
    __shared__ alignas(16) char lds8[2 * 65536];
    const int bx  = blockIdx.x;                 // 0..255
    const int swz = (bx & 7) * 32 + (bx >> 3);  // XCD-bijective (256 % 8 == 0)
    const int y   = blockIdx.y;
    if (y == 0)
        gcore<0>(lds8, qb, Wqb, (void*)pq, bq, nullptr, 1.f, E, E, E, E, swz & 3, swz >> 2, 0, 0);
    else if (y == 1)
        gcore<0>(lds8, kb, Wkb, (void*)pk, bk, nullptr, 1.f, E, E, E, E, swz & 3, swz >> 2, 0, 0);
    else
        gcore<1>(lds8, Wvb, vb, (void*)pvT, bv, nullptr, 1.f, E, E, E, NBL, swz & 63, swz >> 6, 0, 0);
}

// ---------------- S = exp(pq @ pk^T * scale) -> bf16 + row partial sums ----------------
__global__ __launch_bounds__(512, 2) void sgemm_exp(const u16* __restrict__ pq,
                                                    const u16* __restrict__ pk,
                                                    u16* __restrict__ S,
                                                    float* __restrict__ partial,
                                                    float scale, int E, int L, int nrows) {
    __shared__ alignas(16) char lds8[2 * 65536];
    const int gx  = gridDim.x;
    const int nwg = gx * gridDim.y;
    const int wg  = blockIdx.y * gx + blockIdx.x;
    const int swz = (wg & 7) * (nwg >> 3) + (wg >> 3);
    const int tx  = swz % gx, ty = swz / gx;
    const long z  = blockIdx.z;
    gcore<4>(lds8, pq + z * L * E, pk + z * L * E, (void*)(S + z * (long)L * L),
             nullptr, partial, scale, E, E, E, L, tx, ty, z * L, nrows);
}

// ---------------- rinv[i] = 1 / sum_p partial[p][i] ----------------
__global__ __launch_bounds__(256) void rowsum_inv(const float* __restrict__ partial,
                                                  float* __restrict__ rinv, int nrows) {
    int i = blockIdx.x * 256 + threadIdx.x;
    if (i < nrows) {
        float s = 0.f;
#pragma unroll 8
        for (int p = 0; p < 64; ++p) s += partial[(long)p * nrows + i];
        rinv[i] = 1.f / s;
    }
}

// ---------------- out = (S @ pvT^T) * rinv[row], fp32 ----------------
__global__ __launch_bounds__(512, 2) void pv_gemm(const u16* __restrict__ S,
                                                  const u16* __restrict__ pvT,
                                                  float* __restrict__ out,
                                                  float* __restrict__ rinv,
                                                  int L, int E, int NBL, int nrows) {
    __shared__ alignas(16) char lds8[2 * 65536];
    const int gx  = gridDim.x;
    const int nwg = gx * gridDim.y;
    const int wg  = blockIdx.y * gx + blockIdx.x;
    const int swz = (wg & 7) * (nwg >> 3) + (wg >> 3);
    const int tx  = swz % gx, ty = swz / gx;
    const long z  = blockIdx.z;
    gcore<5>(lds8, S + z * (long)L * L, pvT + z * L, (void*)(out + z * (long)L * E),
             nullptr, rinv, 1.f, L, L, NBL, E, tx, ty, z * L, nrows);
}

extern "C" void kernel_launch(void* const* d_in, const int* in_sizes, int n_in,
                              void* d_out, int out_size, void* d_ws, size_t ws_size,
                              hipStream_t stream) {
    (void)in_sizes; (void)n_in; (void)out_size;
    const float* q  = (const float*)d_in[0];
    const float* k  = (const float*)d_in[1];
    const float* v  = (const float*)d_in[2];
    const float* Wq = (const float*)d_in[3];
    const float* bq = (const float*)d_in[4];
    const float* Wk = (const float*)d_in[5];
    const float* bk = (const float*)d_in[6];
    const float* Wv = (const float*)d_in[7];
    const float* bv = (const float*)d_in[8];
    float* out = (float*)d_out;

    constexpr long MB = 1l << 20;
    char* ws = (char*)d_ws;
    u16* pq   = (u16*)(ws + 0 * MB);    // 32 MB  [16384,1024] bf16
    u16* pk   = (u16*)(ws + 32 * MB);   // 32 MB
    u16* pvT  = (u16*)(ws + 64 * MB);   // 32 MB  [1024,16384] bf16
    u16* Wqb  = (u16*)(ws + 96 * MB);   // 2 MB (dead after proj3)
    u16* Wkb  = (u16*)(ws + 98 * MB);   // 2 MB
    u16* Wvb  = (u16*)(ws + 100 * MB);  // 2 MB
    float* partial = (float*)(ws + 96 * MB);   // 4 MB, aliases Wqb/Wkb (dead)
    float* rinv    = (float*)(ws + 100 * MB);  // 64 KB, aliases Wvb (dead)
    u16* qb   = (u16*)(ws + 104 * MB);  // 32 MB (dead after proj3)
    u16* kb   = (u16*)(ws + 136 * MB);  // 32 MB
    u16* vb   = (u16*)(ws + 168 * MB);  // 32 MB
    u16* S4   = (u16*)(ws + 104 * MB);  // z4: 128 MB (104..232), aliases qb/kb/vb

    const int L = 4096, E = 1024, NB = 4;
    const int n8_x = (NB * L * E) / 8;
    const int n8_w = (E * E) / 8;
    const bool z4 = ws_size >= (size_t)233 * MB;

    cvt6<<<dim3(1024, 6), 256, 0, stream>>>(q, k, v, Wq, Wk, Wv,
                                            qb, kb, vb, Wqb, Wkb, Wvb, n8_x, n8_w);

    // all three projections, one dispatch (768 blocks)
    proj3<<<dim3(256, 3), 512, 0, stream>>>(qb, kb, vb, Wqb, Wkb, Wvb,
                                            pq, pk, pvT, bq, bk, bv, E, NB * L);

    const float scale = 0.03125f;  // 1/sqrt(1024)
    if (z4) {
        const int nrows = NB * L;  // 16384
        sgemm_exp<<<dim3(16, 16, 4), 512, 0, stream>>>(pq, pk, S4, partial, scale, E, L, nrows);
        rowsum_inv<<<nrows / 256, 256, 0, stream>>>(partial, rinv, nrows);
        pv_gemm<<<dim3(4, 16, 4), 512, 0, stream>>>(S4, pvT, out, rinv, L, E, NB * L, nrows);
    } else {
        u16* S2 = S4;  // 64 MB, 2 batches at a time
        const int nrows = 2 * L;   // 8192
        for (int p = 0; p < 2; ++p) {
            const long zb = p * 2;
            sgemm_exp<<<dim3(16, 16, 2), 512, 0, stream>>>(pq + zb * L * E, pk + zb * L * E,
                                                           S2, partial, scale, E, L, nrows);
            rowsum_inv<<<nrows / 256, 256, 0, stream>>>(partial, rinv, nrows);
            pv_gemm<<<dim3(4, 16, 2), 512, 0, stream>>>(S2, pvT + zb * L, out + zb * L * E,
                                                        rinv, L, E, NB * L, nrows);
        }
    }
}